// Round 1
// baseline (623.563 us; speedup 1.0000x reference)
//
#include <hip/hip_runtime.h>
#include <hip/hip_bf16.h>
#include <stdint.h>

typedef __attribute__((ext_vector_type(8))) short short8;
typedef __attribute__((ext_vector_type(4))) float floatx4;

typedef __attribute__((address_space(1))) const uint32_t ga_u32;
typedef __attribute__((address_space(3))) uint32_t ls_u32;

static constexpr int NB = 32, ND = 256, NH = 32, NW = 32;
static constexpr int NROWS = NB * NH * NW;        // 32768
static constexpr int NCODE = 8192;
static constexpr int QELEMS = NB * ND * NH * NW;  // 8388608

// ---------------- prep: z (b,d,h,w) -> zh/zl [n][d] bf16 split ----------------
__global__ __launch_bounds__(256) void prep_z(const float* __restrict__ z,
                                              __hip_bfloat16* __restrict__ zh,
                                              __hip_bfloat16* __restrict__ zl)
{
  __shared__ float tile[32][257];
  const int t = threadIdx.x;
  const int b = blockIdx.x;
  const int d0 = blockIdx.y * 32;
  const int hw0 = blockIdx.z * 256;
  const float* src = z + (((size_t)b * 256 + d0) << 10) + hw0;
#pragma unroll
  for (int i = 0; i < 32; ++i)
    tile[i][t] = src[((size_t)i << 10) + t];
  __syncthreads();
  const int c = t & 31;
  const int rbase = t >> 5;
#pragma unroll
  for (int rr = 0; rr < 32; ++rr) {
    int r = rr * 8 + rbase;
    float v = tile[c][r];
    __hip_bfloat16 hi = __float2bfloat16(v);
    float hif = __bfloat162float(hi);
    __hip_bfloat16 lo = __float2bfloat16(v - hif);
    size_t idx = ((size_t)b * 1024 + hw0 + r) * 256 + d0 + c;
    zh[idx] = hi;
    zl[idx] = lo;
  }
}

// ---------------- prep: codebook -> ch/cl bf16 split + fp32 norms ----------------
__global__ __launch_bounds__(256) void prep_cb(const float* __restrict__ cb,
                                               __hip_bfloat16* __restrict__ chv,
                                               __hip_bfloat16* __restrict__ clv,
                                               float* __restrict__ norms)
{
  const int k = blockIdx.x;
  const int t = threadIdx.x;
  float v = cb[((size_t)k << 8) + t];
  __hip_bfloat16 hi = __float2bfloat16(v);
  float hif = __bfloat162float(hi);
  chv[((size_t)k << 8) + t] = hi;
  clv[((size_t)k << 8) + t] = __float2bfloat16(v - hif);
  float s = v * v;
#pragma unroll
  for (int off = 32; off; off >>= 1) s += __shfl_down(s, off);
  __shared__ float ps[4];
  if ((t & 63) == 0) ps[t >> 6] = s;
  __syncthreads();
  if (t == 0) norms[k] = ps[0] + ps[1] + ps[2] + ps[3];
}

// ---------------- init argmin array ----------------
__global__ __launch_bounds__(256) void init_ws(unsigned long long* __restrict__ amin)
{
  int i = blockIdx.x * 256 + threadIdx.x;
  if (i < NROWS) amin[i] = ~0ull;
}

// ---------------- main: 3-split bf16 GEMM + fused argmin ----------------
__global__ __launch_bounds__(256) void gemm_argmin(
    const __hip_bfloat16* __restrict__ zh, const __hip_bfloat16* __restrict__ zl,
    const __hip_bfloat16* __restrict__ chv, const __hip_bfloat16* __restrict__ clv,
    const float* __restrict__ norms, unsigned long long* __restrict__ amin)
{
  __shared__ alignas(16) unsigned short As[128 * 32];  // [row][k] 64B rows
  __shared__ alignas(16) unsigned short Bs[128 * 32];  // [code][k]

  const int t = threadIdx.x;
  const int lane = t & 63;
  const int wid = t >> 6;
  const int wm = wid >> 1;
  const int wn = wid & 1;
  const int m0 = blockIdx.x * 128;
  const int n0 = blockIdx.y * 128;

  floatx4 acc[4][4];
#pragma unroll
  for (int i = 0; i < 4; ++i)
#pragma unroll
    for (int j = 0; j < 4; ++j)
      acc[i][j] = (floatx4){0.f, 0.f, 0.f, 0.f};

  const int beta0 = wid * 2048 + lane * 16;  // this thread's 16B staging chunk

  for (int s = 0; s < 3; ++s) {
    const __hip_bfloat16* aseg = (s == 2) ? zl : zh;  // products: zh*ch, zh*cl, zl*ch
    const __hip_bfloat16* bseg = (s == 1) ? clv : chv;
    for (int k0 = 0; k0 < 256; k0 += 32) {
      __syncthreads();  // previous compute done reading LDS
#pragma unroll
      for (int j = 0; j < 2; ++j) {
        int beta = beta0 + j * 1024;
        int row = beta >> 6;
        int cole = (beta & 63) >> 1;
        const __hip_bfloat16* ga = aseg + ((size_t)(m0 + row) << 8) + k0 + cole;
        __builtin_amdgcn_global_load_lds((ga_u32*)ga, (ls_u32*)(As + (beta >> 1)), 16, 0, 0);
        const __hip_bfloat16* gb = bseg + ((size_t)(n0 + row) << 8) + k0 + cole;
        __builtin_amdgcn_global_load_lds((ga_u32*)gb, (ls_u32*)(Bs + (beta >> 1)), 16, 0, 0);
      }
      __syncthreads();  // drains vmcnt before barrier (compiler-emitted)

      short8 a[4], b[4];
#pragma unroll
      for (int i = 0; i < 4; ++i) {
        int row = wm * 64 + i * 16 + (lane & 15);
        a[i] = *(const short8*)&As[row * 32 + ((lane >> 4) << 3)];
        int code = wn * 64 + i * 16 + (lane & 15);
        b[i] = *(const short8*)&Bs[code * 32 + ((lane >> 4) << 3)];
      }
#pragma unroll
      for (int i = 0; i < 4; ++i)
#pragma unroll
        for (int j = 0; j < 4; ++j)
          acc[i][j] = __builtin_amdgcn_mfma_f32_16x16x32_bf16(a[i], b[j], acc[i][j], 0, 0, 0);
    }
  }

  // epilogue: score = ||c||^2 - 2*dot; per-row argmin, tie -> smaller code
  float nrm[4];
#pragma unroll
  for (int j = 0; j < 4; ++j)
    nrm[j] = norms[n0 + wn * 64 + j * 16 + (lane & 15)];

#pragma unroll
  for (int i = 0; i < 4; ++i) {
#pragma unroll
    for (int r = 0; r < 4; ++r) {
      int row = m0 + wm * 64 + i * 16 + ((lane >> 4) << 2) + r;
      unsigned long long best = ~0ull;
#pragma unroll
      for (int j = 0; j < 4; ++j) {
        int code = n0 + wn * 64 + j * 16 + (lane & 15);
        float sc = nrm[j] - 2.0f * acc[i][j][r];
        uint32_t u = __float_as_uint(sc);
        u = (u & 0x80000000u) ? ~u : (u | 0x80000000u);  // sortable float
        unsigned long long p = ((unsigned long long)u << 32) | (uint32_t)code;
        best = p < best ? p : best;
      }
#pragma unroll
      for (int off = 1; off < 16; off <<= 1) {  // reduce over the 16 codes held per lane-group
        uint32_t lo = (uint32_t)best, hi = (uint32_t)(best >> 32);
        lo = (uint32_t)__shfl_xor((int)lo, off);
        hi = (uint32_t)__shfl_xor((int)hi, off);
        unsigned long long o = ((unsigned long long)hi << 32) | lo;
        best = o < best ? o : best;
      }
      if ((lane & 15) == 0)
        atomicMin(&amin[row], best);
    }
  }
}

// ---------------- gather + output + per-block loss partials ----------------
__global__ __launch_bounds__(256) void gather_out(
    const float* __restrict__ z, const float* __restrict__ cb,
    const unsigned long long* __restrict__ amin,
    float* __restrict__ out, float* __restrict__ partial)
{
  const int t = threadIdx.x;
  const int e = blockIdx.x * 256 + t;
  const int d = (e >> 10) & 255;
  const int b = e >> 18;
  const int n = (b << 10) | (e & 1023);
  const uint32_t k = (uint32_t)amin[n];
  const float q = cb[((size_t)k << 8) + d];
  out[e] = q;  // q_st == quantized in value (straight-through)
  const float diff = z[e] - q;
  float s = diff * diff;
#pragma unroll
  for (int off = 32; off; off >>= 1) s += __shfl_down(s, off);
  __shared__ float ps[4];
  if ((t & 63) == 0) ps[t >> 6] = s;
  __syncthreads();
  if (t == 0) partial[blockIdx.x] = ps[0] + ps[1] + ps[2] + ps[3];
}

// ---------------- deterministic final reduction + scalar outputs ----------------
__global__ __launch_bounds__(256) void finalize(const float* __restrict__ partial,
                                                float* __restrict__ out)
{
  const int t = threadIdx.x;
  float s = 0.f;
  for (int i = t; i < QELEMS / 256; i += 256) s += partial[i];
#pragma unroll
  for (int off = 32; off; off >>= 1) s += __shfl_down(s, off);
  __shared__ float ps[4];
  if ((t & 63) == 0) ps[t >> 6] = s;
  __syncthreads();
  if (t == 0) {
    float m = (ps[0] + ps[1] + ps[2] + ps[3]) / (float)QELEMS;
    out[QELEMS] = m;           // codebook_loss
    out[QELEMS + 1] = 0.2f * m;  // commitment_loss = BETA * same mean
  }
}

extern "C" void kernel_launch(void* const* d_in, const int* in_sizes, int n_in,
                              void* d_out, int out_size, void* d_ws, size_t ws_size,
                              hipStream_t stream)
{
  const float* z = (const float*)d_in[0];
  const float* cb = (const float*)d_in[1];
  float* out = (float*)d_out;
  char* ws = (char*)d_ws;

  // ws layout (bytes)
  __hip_bfloat16* zh = (__hip_bfloat16*)(ws + 0);                    // 16,777,216
  __hip_bfloat16* zl = (__hip_bfloat16*)(ws + 16777216);             // 16,777,216
  __hip_bfloat16* chv = (__hip_bfloat16*)(ws + 33554432);            //  4,194,304
  __hip_bfloat16* clv = (__hip_bfloat16*)(ws + 37748736);            //  4,194,304
  float* norms = (float*)(ws + 41943040);                            //     32,768
  unsigned long long* amin = (unsigned long long*)(ws + 41975808);   //    262,144
  float* partial = (float*)(ws + 42237952);                          //    131,072
  // total: 42,369,024 bytes

  prep_z<<<dim3(32, 8, 4), 256, 0, stream>>>(z, zh, zl);
  prep_cb<<<NCODE, 256, 0, stream>>>(cb, chv, clv, norms);
  init_ws<<<NROWS / 256, 256, 0, stream>>>(amin);
  gemm_argmin<<<dim3(NROWS / 128, NCODE / 128), 256, 0, stream>>>(zh, zl, chv, clv, norms, amin);
  gather_out<<<QELEMS / 256, 256, 0, stream>>>(z, cb, amin, out, partial);
  finalize<<<1, 256, 0, stream>>>(partial, out);
}

// Round 2
// 271.441 us; speedup vs baseline: 2.2972x; 2.2972x over previous
//
#include <hip/hip_runtime.h>
#include <hip/hip_bf16.h>
#include <stdint.h>

typedef __attribute__((ext_vector_type(8))) short short8;
typedef __attribute__((ext_vector_type(4))) float floatx4;

typedef __attribute__((address_space(1))) const uint32_t ga_u32;
typedef __attribute__((address_space(3))) uint32_t ls_u32;

static constexpr int NB = 32, ND = 256, NH = 32, NW = 32;
static constexpr int NROWS = NB * NH * NW;        // 32768
static constexpr int NCODE = 8192;
static constexpr int QELEMS = NB * ND * NH * NW;  // 8388608

// ---------------- prep: z (b,d,h,w) -> zh [n][d] bf16 ----------------
__global__ __launch_bounds__(256) void prep_z(const float* __restrict__ z,
                                              __hip_bfloat16* __restrict__ zh)
{
  __shared__ float tile[32][257];
  const int t = threadIdx.x;
  const int b = blockIdx.x;
  const int d0 = blockIdx.y * 32;
  const int hw0 = blockIdx.z * 256;
  const float* src = z + (((size_t)b * 256 + d0) << 10) + hw0;
#pragma unroll
  for (int i = 0; i < 32; ++i)
    tile[i][t] = src[((size_t)i << 10) + t];
  __syncthreads();
  const int c = t & 31;
  const int rbase = t >> 5;
#pragma unroll
  for (int rr = 0; rr < 32; ++rr) {
    int r = rr * 8 + rbase;
    float v = tile[c][r];
    zh[((size_t)b * 1024 + hw0 + r) * 256 + d0 + c] = __float2bfloat16(v);
  }
}

// ---------------- prep: codebook -> ch bf16 + fp32 norms ----------------
__global__ __launch_bounds__(256) void prep_cb(const float* __restrict__ cb,
                                               __hip_bfloat16* __restrict__ chv,
                                               float* __restrict__ norms)
{
  const int k = blockIdx.x;
  const int t = threadIdx.x;
  float v = cb[((size_t)k << 8) + t];
  chv[((size_t)k << 8) + t] = __float2bfloat16(v);
  float s = v * v;
#pragma unroll
  for (int off = 32; off; off >>= 1) s += __shfl_down(s, off);
  __shared__ float ps[4];
  if ((t & 63) == 0) ps[t >> 6] = s;
  __syncthreads();
  if (t == 0) norms[k] = ps[0] + ps[1] + ps[2] + ps[3];
}

// ---------------- init argmin array ----------------
__global__ __launch_bounds__(256) void init_ws(unsigned long long* __restrict__ amin)
{
  int i = blockIdx.x * 256 + threadIdx.x;
  if (i < NROWS) amin[i] = ~0ull;
}

// ---------------- main: bf16 GEMM (swapped operands) + fused argmin ----------------
// D[code][zrow] = mfma(code_frag, z_frag, acc): each lane holds 16 candidate
// codes for a single z-row -> in-register argmin scan, 2 shfl steps, 1 atomic.
__global__ __launch_bounds__(256) void gemm_argmin(
    const __hip_bfloat16* __restrict__ zh, const __hip_bfloat16* __restrict__ chv,
    const float* __restrict__ norms, unsigned long long* __restrict__ amin)
{
  __shared__ alignas(16) unsigned short As[128 * 32];  // [zrow][k], 64B rows, chunk-swizzled
  __shared__ alignas(16) unsigned short Bs[128 * 32];  // [code][k], same swizzle

  const int t = threadIdx.x;
  const int lane = t & 63;
  const int wid = t >> 6;
  const int wm = wid >> 1;   // z-row half
  const int wn = wid & 1;    // code half
  const int m0 = blockIdx.x * 128;
  const int n0 = blockIdx.y * 128;

  floatx4 acc[4][4];  // [code subtile][zrow subtile]
#pragma unroll
  for (int i = 0; i < 4; ++i)
#pragma unroll
    for (int j = 0; j < 4; ++j)
      acc[i][j] = (floatx4){0.f, 0.f, 0.f, 0.f};

  // staging: thread's 16B chunk; LDS dest linear, global source chunk-XOR-swizzled
  const int beta0 = wid * 2048 + lane * 16;                  // LDS byte offset
  const int srow0 = wid * 32 + (lane >> 2);                  // tile row being staged
  const int scole = (((lane & 3) ^ ((lane >> 3) & 3)) << 3); // swizzled K-elem offset
  // frag read: logical chunk (lane>>4) lives at physical chunk ^ ((row>>1)&3)
  const int rchunk = (((lane >> 4) ^ ((lane >> 1) & 3)) << 3);

  for (int k0 = 0; k0 < 256; k0 += 32) {
    __syncthreads();
#pragma unroll
    for (int j = 0; j < 2; ++j) {
      int beta = beta0 + j * 1024;
      int srow = srow0 + j * 16;
      const __hip_bfloat16* ga = zh + ((size_t)(m0 + srow) << 8) + k0 + scole;
      __builtin_amdgcn_global_load_lds((ga_u32*)ga, (ls_u32*)(As + (beta >> 1)), 16, 0, 0);
      const __hip_bfloat16* gb = chv + ((size_t)(n0 + srow) << 8) + k0 + scole;
      __builtin_amdgcn_global_load_lds((ga_u32*)gb, (ls_u32*)(Bs + (beta >> 1)), 16, 0, 0);
    }
    __syncthreads();

    short8 cfr[4], zfr[4];
#pragma unroll
    for (int i = 0; i < 4; ++i) {
      int zr = wm * 64 + i * 16 + (lane & 15);
      zfr[i] = *(const short8*)&As[zr * 32 + rchunk];
      int cd = wn * 64 + i * 16 + (lane & 15);
      cfr[i] = *(const short8*)&Bs[cd * 32 + rchunk];
    }
#pragma unroll
    for (int i = 0; i < 4; ++i)
#pragma unroll
      for (int j = 0; j < 4; ++j)
        acc[i][j] = __builtin_amdgcn_mfma_f32_16x16x32_bf16(cfr[i], zfr[j], acc[i][j], 0, 0, 0);
  }

  // epilogue: lane holds 16 codes (i,g,r) for z-row (j, lane&15)
  const int g = lane >> 4;
  float nrm[4][4];
#pragma unroll
  for (int i = 0; i < 4; ++i)
#pragma unroll
    for (int r = 0; r < 4; ++r)
      nrm[i][r] = norms[n0 + wn * 64 + i * 16 + g * 4 + r];

#pragma unroll
  for (int j = 0; j < 4; ++j) {
    float best = __builtin_inff();
    int bc = 0;
    // ascending code order => strict < keeps smallest code on ties
#pragma unroll
    for (int i = 0; i < 4; ++i)
#pragma unroll
      for (int r = 0; r < 4; ++r) {
        float sc = fmaf(acc[i][j][r], -2.0f, nrm[i][r]);
        int cd = n0 + wn * 64 + i * 16 + g * 4 + r;
        if (sc < best) { best = sc; bc = cd; }
      }
    uint32_t u = __float_as_uint(best);
    u ^= ((uint32_t)((int32_t)u >> 31) | 0x80000000u);  // monotone-sortable
    unsigned long long p = ((unsigned long long)u << 32) | (uint32_t)bc;
    // reduce across the 4 lane-groups holding the same z-row
#pragma unroll
    for (int off = 16; off < 64; off <<= 1) {
      unsigned long long o = (unsigned long long)__shfl_xor((long long)p, off);
      p = o < p ? o : p;
    }
    if (lane < 16)
      atomicMin(&amin[m0 + wm * 64 + j * 16 + lane], p);
  }
}

// ---------------- gather + output + per-block loss partials ----------------
__global__ __launch_bounds__(256) void gather_out(
    const float* __restrict__ z, const float* __restrict__ cb,
    const unsigned long long* __restrict__ amin,
    float* __restrict__ out, float* __restrict__ partial)
{
  const int t = threadIdx.x;
  const int e = blockIdx.x * 256 + t;
  const int d = (e >> 10) & 255;
  const int b = e >> 18;
  const int n = (b << 10) | (e & 1023);
  const uint32_t k = (uint32_t)amin[n];
  const float q = cb[((size_t)k << 8) + d];
  out[e] = q;  // q_st == quantized in value
  const float diff = z[e] - q;
  float s = diff * diff;
#pragma unroll
  for (int off = 32; off; off >>= 1) s += __shfl_down(s, off);
  __shared__ float ps[4];
  if ((t & 63) == 0) ps[t >> 6] = s;
  __syncthreads();
  if (t == 0) partial[blockIdx.x] = ps[0] + ps[1] + ps[2] + ps[3];
}

// ---------------- deterministic final reduction + scalar outputs ----------------
__global__ __launch_bounds__(256) void finalize(const float* __restrict__ partial,
                                                float* __restrict__ out)
{
  const int t = threadIdx.x;
  float s = 0.f;
  for (int i = t; i < QELEMS / 256; i += 256) s += partial[i];
#pragma unroll
  for (int off = 32; off; off >>= 1) s += __shfl_down(s, off);
  __shared__ float ps[4];
  if ((t & 63) == 0) ps[t >> 6] = s;
  __syncthreads();
  if (t == 0) {
    float m = (ps[0] + ps[1] + ps[2] + ps[3]) / (float)QELEMS;
    out[QELEMS] = m;             // codebook_loss
    out[QELEMS + 1] = 0.2f * m;  // commitment_loss
  }
}

extern "C" void kernel_launch(void* const* d_in, const int* in_sizes, int n_in,
                              void* d_out, int out_size, void* d_ws, size_t ws_size,
                              hipStream_t stream)
{
  const float* z = (const float*)d_in[0];
  const float* cb = (const float*)d_in[1];
  float* out = (float*)d_out;
  char* ws = (char*)d_ws;

  // ws layout (bytes)
  __hip_bfloat16* zh = (__hip_bfloat16*)(ws + 0);                   // 16,777,216
  __hip_bfloat16* chv = (__hip_bfloat16*)(ws + 16777216);           //  4,194,304
  float* norms = (float*)(ws + 20971520);                           //     32,768
  unsigned long long* amin = (unsigned long long*)(ws + 21004288);  //    262,144
  float* partial = (float*)(ws + 21266432);                         //    131,072
  // total: 21,397,504 bytes

  prep_z<<<dim3(32, 8, 4), 256, 0, stream>>>(z, zh);
  prep_cb<<<NCODE, 256, 0, stream>>>(cb, chv, norms);
  init_ws<<<NROWS / 256, 256, 0, stream>>>(amin);
  gemm_argmin<<<dim3(NROWS / 128, NCODE / 128), 256, 0, stream>>>(zh, chv, norms, amin);
  gather_out<<<QELEMS / 256, 256, 0, stream>>>(z, cb, amin, out, partial);
  finalize<<<1, 256, 0, stream>>>(partial, out);
}

// Round 3
// 239.371 us; speedup vs baseline: 2.6050x; 1.1340x over previous
//
#include <hip/hip_runtime.h>
#include <hip/hip_bf16.h>
#include <stdint.h>

typedef __attribute__((ext_vector_type(8))) short short8;
typedef __attribute__((ext_vector_type(4))) float floatx4;
typedef __attribute__((ext_vector_type(4))) unsigned int uint4v;
typedef unsigned long long u64;

typedef __attribute__((address_space(1))) const uint32_t ga_u32;
typedef __attribute__((address_space(3))) uint32_t ls_u32;

static constexpr int NROWS = 32768;   // z rows (b*h*w)
static constexpr int NCODE = 8192;
static constexpr int QELEMS = 8388608;

// ---------------- prep: z (b,d,h,w) -> zh [n][d] bf16 ----------------
__global__ __launch_bounds__(256) void prep_z(const float* __restrict__ z,
                                              __hip_bfloat16* __restrict__ zh)
{
  __shared__ float tile[32][257];
  const int t = threadIdx.x;
  const int b = blockIdx.x;
  const int d0 = blockIdx.y * 32;
  const int hw0 = blockIdx.z * 256;
  const float* src = z + (((size_t)b * 256 + d0) << 10) + hw0;
#pragma unroll
  for (int i = 0; i < 32; ++i)
    tile[i][t] = src[((size_t)i << 10) + t];
  __syncthreads();
  const int c = t & 31;
  const int rbase = t >> 5;
#pragma unroll
  for (int rr = 0; rr < 32; ++rr) {
    int r = rr * 8 + rbase;
    zh[((size_t)b * 1024 + hw0 + r) * 256 + d0 + c] = __float2bfloat16(tile[c][r]);
  }
}

// ---------------- prep: codebook -> ch bf16 + fp32 norms ----------------
__global__ __launch_bounds__(256) void prep_cb(const float* __restrict__ cb,
                                               __hip_bfloat16* __restrict__ chv,
                                               float* __restrict__ norms)
{
  const int k = blockIdx.x;
  const int t = threadIdx.x;
  float v = cb[((size_t)k << 8) + t];
  chv[((size_t)k << 8) + t] = __float2bfloat16(v);
  float s = v * v;
#pragma unroll
  for (int off = 32; off; off >>= 1) s += __shfl_down(s, off);
  __shared__ float ps[4];
  if ((t & 63) == 0) ps[t >> 6] = s;
  __syncthreads();
  if (t == 0) norms[k] = ps[0] + ps[1] + ps[2] + ps[3];
}

// ---------------- main: 256x256 tile, BK=32, 4-slot ring, counted vmcnt ----------------
// A = codes (chv), B = zrows (zh); D[code][zrow] = mfma(cfrag, zfrag, acc).
// 8 waves = 2(code) x 4(zrow); per-wave output 128 codes x 64 zrows -> acc[8][4].
__global__ __launch_bounds__(512, 2) void gemm_argmin(
    const __hip_bfloat16* __restrict__ zh, const __hip_bfloat16* __restrict__ chv,
    const float* __restrict__ norms, u64* __restrict__ partial)
{
  // 4 slots x (A: 8192 ushort, B: 8192 ushort) = 128 KiB
  __shared__ alignas(16) unsigned short lds[4 * 16384];

  const int tid = threadIdx.x;
  const int lane = tid & 63;
  const int wid = tid >> 6;
  const int wm = wid >> 2;  // code half: 0..1 (128 codes)
  const int wn = wid & 3;   // zrow quarter: 0..3 (64 zrows)

  // XCD chunked swizzle (nwg = 4096, divisible by 8)
  const int bid = blockIdx.x;
  const int swz = (bid & 7) * 512 + (bid >> 3);
  const int cx = swz & 31;   // code block
  const int cy = swz >> 5;   // zrow block
  const int m0 = cx * 256;
  const int n0 = cy * 256;

  const int q = lane & 15;
  const int g = lane >> 4;
  const int rchunk = ((g ^ ((q >> 1) & 3)) << 3);  // swizzled 16B chunk, ushort units

  // staging constants: thread stages 16B at lds byte tid*16 (+8192 for L=1)
  const int srow = tid >> 2;                               // 0..127
  const int koff = (((tid & 3) ^ ((srow >> 1) & 3)) << 3); // swizzled k-elem offset

  floatx4 acc[8][4];
#pragma unroll
  for (int i = 0; i < 8; ++i)
#pragma unroll
    for (int j = 0; j < 4; ++j)
      acc[i][j] = (floatx4){0.f, 0.f, 0.f, 0.f};

  auto STAGE_A = [&](int kt) {
    unsigned short* s0 = lds + (kt & 3) * 16384 + tid * 8;
    const __hip_bfloat16* g0 = chv + ((size_t)(m0 + srow) << 8) + kt * 32 + koff;
    __builtin_amdgcn_global_load_lds((ga_u32*)g0, (ls_u32*)s0, 16, 0, 0);
    const __hip_bfloat16* g1 = g0 + (128 << 8);
    __builtin_amdgcn_global_load_lds((ga_u32*)g1, (ls_u32*)(s0 + 4096), 16, 0, 0);
  };
  auto STAGE_B = [&](int kt) {
    unsigned short* s0 = lds + (kt & 3) * 16384 + 8192 + tid * 8;
    const __hip_bfloat16* g0 = zh + ((size_t)(n0 + srow) << 8) + kt * 32 + koff;
    __builtin_amdgcn_global_load_lds((ga_u32*)g0, (ls_u32*)s0, 16, 0, 0);
    const __hip_bfloat16* g1 = g0 + (128 << 8);
    __builtin_amdgcn_global_load_lds((ga_u32*)g1, (ls_u32*)(s0 + 4096), 16, 0, 0);
  };
  auto LDA = [&](int slot, int i) -> short8 {
    int row = wm * 128 + i * 16 + q;
    return *(const short8*)(lds + slot * 16384 + row * 32 + rchunk);
  };
  auto LDB = [&](int slot, int j) -> short8 {
    int row = wn * 64 + j * 16 + q;
    return *(const short8*)(lds + slot * 16384 + 8192 + row * 32 + rchunk);
  };

  // prologue: stage K-tiles 0 and 1; wait kt0 landed (kt1's 4 stay in flight)
  STAGE_A(0); STAGE_B(0);
  STAGE_A(1); STAGE_B(1);
  asm volatile("s_waitcnt vmcnt(4)" ::: "memory");
  __builtin_amdgcn_s_barrier();

#pragma unroll
  for (int kt = 0; kt < 8; ++kt) {
    const int slot = kt & 3;
    short8 bf[4], af[4];
    // ---- phase 0: read B(j0-3) + A(i0-3); prefetch A of kt+2 ----
#pragma unroll
    for (int j = 0; j < 4; ++j) bf[j] = LDB(slot, j);
#pragma unroll
    for (int i = 0; i < 4; ++i) af[i] = LDA(slot, i);
    if (kt + 2 < 8) STAGE_A(kt + 2);
    asm volatile("" ::: "memory");
    __builtin_amdgcn_s_barrier();
    __builtin_amdgcn_s_setprio(1);
#pragma unroll
    for (int i = 0; i < 4; ++i)
#pragma unroll
      for (int j = 0; j < 4; ++j)
        acc[i][j] = __builtin_amdgcn_mfma_f32_16x16x32_bf16(af[i], bf[j], acc[i][j], 0, 0, 0);
    __builtin_amdgcn_s_setprio(0);
    asm volatile("" ::: "memory");
    __builtin_amdgcn_s_barrier();
    // ---- phase 1: read A(i4-7), reuse B; prefetch B of kt+2 ----
#pragma unroll
    for (int i = 0; i < 4; ++i) af[i] = LDA(slot, 4 + i);
    if (kt + 2 < 8) STAGE_B(kt + 2);
    asm volatile("" ::: "memory");
    __builtin_amdgcn_s_barrier();
    __builtin_amdgcn_s_setprio(1);
#pragma unroll
    for (int i = 0; i < 4; ++i)
#pragma unroll
      for (int j = 0; j < 4; ++j)
        acc[4 + i][j] = __builtin_amdgcn_mfma_f32_16x16x32_bf16(af[i], bf[j], acc[4 + i][j], 0, 0, 0);
    __builtin_amdgcn_s_setprio(0);
    // ---- kt boundary: next tile must be landed; keep kt+2's 4 loads in flight ----
    if (kt < 6) {
      asm volatile("s_waitcnt vmcnt(4)" ::: "memory");
    } else if (kt == 6) {
      asm volatile("s_waitcnt vmcnt(0)" ::: "memory");
    }
    asm volatile("" ::: "memory");
    __builtin_amdgcn_s_barrier();
  }

  // ---- epilogue: fused argmin (deterministic, no atomics) ----
  float nrm[8][4];
#pragma unroll
  for (int i = 0; i < 8; ++i)
#pragma unroll
    for (int r = 0; r < 4; ++r)
      nrm[i][r] = norms[m0 + wm * 128 + i * 16 + g * 4 + r];

  u64* best2 = (u64*)lds;  // [256 zrows][2 wm]
#pragma unroll
  for (int j = 0; j < 4; ++j) {
    float best = __builtin_inff();
    int bc = 0;
    // ascending code order => strict < keeps smallest code on ties
#pragma unroll
    for (int i = 0; i < 8; ++i)
#pragma unroll
      for (int r = 0; r < 4; ++r) {
        float sc = fmaf(acc[i][j][r], -2.0f, nrm[i][r]);
        int cd = m0 + wm * 128 + i * 16 + g * 4 + r;
        if (sc < best) { best = sc; bc = cd; }
      }
    uint32_t u = __float_as_uint(best);
    u ^= ((uint32_t)((int32_t)u >> 31) | 0x80000000u);  // monotone-sortable
    u64 p = ((u64)u << 32) | (uint32_t)bc;
#pragma unroll
    for (int off = 16; off < 64; off <<= 1) {
      u64 o = (u64)__shfl_xor((long long)p, off);
      p = o < p ? o : p;
    }
    if (lane < 16) best2[(size_t)(wn * 64 + j * 16 + lane) * 2 + wm] = p;
  }
  __syncthreads();
  if (tid < 256) {
    u64 a = best2[tid * 2], b = best2[tid * 2 + 1];
    partial[(size_t)cx * NROWS + n0 + tid] = a < b ? a : b;
  }
}

// ---------------- stage-2: reduce 32 code-block partials -> final code ----------------
__global__ __launch_bounds__(256) void reduce_amin(const u64* __restrict__ partial,
                                                   uint32_t* __restrict__ codei)
{
  const int n = blockIdx.x * 256 + threadIdx.x;
  u64 m = partial[n];
#pragma unroll 4
  for (int x = 1; x < 32; ++x) {
    u64 v = partial[(size_t)x * NROWS + n];
    m = v < m ? v : m;
  }
  codei[n] = (uint32_t)m;
}

// ---------------- gather + output + per-block loss partials (x4 vectorized) ----------------
__global__ __launch_bounds__(256) void gather_out(
    const float* __restrict__ z, const float* __restrict__ cb,
    const uint32_t* __restrict__ codei,
    float* __restrict__ out, float* __restrict__ partial)
{
  const int t = threadIdx.x;
  const int e0 = (blockIdx.x * 256 + t) * 4;
  const int d = (e0 >> 10) & 255;
  const int nb = (e0 >> 18) << 10;  // b*1024
  const int hw = e0 & 1023;
  floatx4 zv = *(const floatx4*)&z[e0];
  uint4v kv = *(const uint4v*)&codei[nb + hw];
  floatx4 qv;
#pragma unroll
  for (int m = 0; m < 4; ++m)
    qv[m] = cb[((size_t)kv[m] << 8) + d];
  *(floatx4*)&out[e0] = qv;
  float s = 0.f;
#pragma unroll
  for (int m = 0; m < 4; ++m) {
    float df = zv[m] - qv[m];
    s += df * df;
  }
#pragma unroll
  for (int off = 32; off; off >>= 1) s += __shfl_down(s, off);
  __shared__ float ps[4];
  if ((t & 63) == 0) ps[t >> 6] = s;
  __syncthreads();
  if (t == 0) partial[blockIdx.x] = ps[0] + ps[1] + ps[2] + ps[3];
}

// ---------------- deterministic final reduction + scalar outputs ----------------
__global__ __launch_bounds__(256) void finalize(const float* __restrict__ partial,
                                                float* __restrict__ out)
{
  const int t = threadIdx.x;
  float s = 0.f;
  for (int i = t; i < QELEMS / 1024; i += 256) s += partial[i];
#pragma unroll
  for (int off = 32; off; off >>= 1) s += __shfl_down(s, off);
  __shared__ float ps[4];
  if ((t & 63) == 0) ps[t >> 6] = s;
  __syncthreads();
  if (t == 0) {
    float m = (ps[0] + ps[1] + ps[2] + ps[3]) / (float)QELEMS;
    out[QELEMS] = m;             // codebook_loss
    out[QELEMS + 1] = 0.2f * m;  // commitment_loss
  }
}

extern "C" void kernel_launch(void* const* d_in, const int* in_sizes, int n_in,
                              void* d_out, int out_size, void* d_ws, size_t ws_size,
                              hipStream_t stream)
{
  const float* z = (const float*)d_in[0];
  const float* cb = (const float*)d_in[1];
  float* out = (float*)d_out;
  char* ws = (char*)d_ws;

  // ws layout (bytes)
  __hip_bfloat16* zh = (__hip_bfloat16*)(ws + 0);        // 16,777,216
  __hip_bfloat16* chv = (__hip_bfloat16*)(ws + 16777216); //  4,194,304
  float* norms = (float*)(ws + 20971520);                 //     32,768
  u64* pamin = (u64*)(ws + 21004288);                     //  8,388,608 (32 x 32768 u64)
  uint32_t* codei = (uint32_t*)(ws + 29392896);           //    131,072
  float* lpart = (float*)(ws + 29523968);                 //     32,768
  // total: 29,556,736 bytes

  prep_z<<<dim3(32, 8, 4), 256, 0, stream>>>(z, zh);
  prep_cb<<<NCODE, 256, 0, stream>>>(cb, chv, norms);
  gemm_argmin<<<4096, 512, 0, stream>>>(zh, chv, norms, pamin);
  reduce_amin<<<NROWS / 256, 256, 0, stream>>>(pamin, codei);
  gather_out<<<QELEMS / 1024, 256, 0, stream>>>(z, cb, codei, out, lpart);
  finalize<<<1, 256, 0, stream>>>(lpart, out);
}

// Round 4
// 238.405 us; speedup vs baseline: 2.6156x; 1.0041x over previous
//
#include <hip/hip_runtime.h>
#include <hip/hip_bf16.h>
#include <stdint.h>

typedef __attribute__((ext_vector_type(8))) short short8;
typedef __attribute__((ext_vector_type(4))) float floatx4;
typedef __attribute__((ext_vector_type(4))) unsigned int uint4v;
typedef unsigned long long u64;

typedef __attribute__((address_space(1))) const uint32_t ga_u32;
typedef __attribute__((address_space(3))) uint32_t ls_u32;

static constexpr int NROWS = 32768;   // z rows (b*h*w)
static constexpr int NCODE = 8192;
static constexpr int QELEMS = 8388608;

// ---------------- prep: z (b,d,h,w) -> zh [n][d] bf16 ----------------
__global__ __launch_bounds__(256) void prep_z(const float* __restrict__ z,
                                              __hip_bfloat16* __restrict__ zh)
{
  __shared__ float tile[32][257];
  const int t = threadIdx.x;
  const int b = blockIdx.x;
  const int d0 = blockIdx.y * 32;
  const int hw0 = blockIdx.z * 256;
  const float* src = z + (((size_t)b * 256 + d0) << 10) + hw0;
#pragma unroll
  for (int i = 0; i < 32; ++i)
    tile[i][t] = src[((size_t)i << 10) + t];
  __syncthreads();
  const int c = t & 31;
  const int rbase = t >> 5;
#pragma unroll
  for (int rr = 0; rr < 32; ++rr) {
    int r = rr * 8 + rbase;
    zh[((size_t)b * 1024 + hw0 + r) * 256 + d0 + c] = __float2bfloat16(tile[c][r]);
  }
}

// ---------------- prep: codebook -> ch bf16 + fp32 norms ----------------
__global__ __launch_bounds__(256) void prep_cb(const float* __restrict__ cb,
                                               __hip_bfloat16* __restrict__ chv,
                                               float* __restrict__ norms)
{
  const int k = blockIdx.x;
  const int t = threadIdx.x;
  float v = cb[((size_t)k << 8) + t];
  chv[((size_t)k << 8) + t] = __float2bfloat16(v);
  float s = v * v;
#pragma unroll
  for (int off = 32; off; off >>= 1) s += __shfl_down(s, off);
  __shared__ float ps[4];
  if ((t & 63) == 0) ps[t >> 6] = s;
  __syncthreads();
  if (t == 0) norms[k] = ps[0] + ps[1] + ps[2] + ps[3];
}

// ---------------- main: 256x256 tile, BK=32, 4-slot ring, 1 barrier/kt ----------------
// A = codes (chv), B = zrows (zh); D[code][zrow] = mfma(cfrag, zfrag, acc).
// 8 waves = 2(code) x 4(zrow); per-wave output 128 codes x 64 zrows -> acc[8][4].
__global__ __launch_bounds__(512, 2) void gemm_argmin(
    const __hip_bfloat16* __restrict__ zh, const __hip_bfloat16* __restrict__ chv,
    const float* __restrict__ norms, u64* __restrict__ partial)
{
  // 4 slots x (A: 8192 ushort, B: 8192 ushort) = 128 KiB
  __shared__ alignas(16) unsigned short lds[4 * 16384];

  const int tid = threadIdx.x;
  const int lane = tid & 63;
  const int wid = tid >> 6;
  const int wm = wid >> 2;  // code half: 0..1 (128 codes)
  const int wn = wid & 3;   // zrow quarter: 0..3 (64 zrows)

  // XCD chunked swizzle (nwg = 4096, divisible by 8)
  const int bid = blockIdx.x;
  const int swz = (bid & 7) * 512 + (bid >> 3);
  const int cx = swz & 31;   // code block
  const int cy = swz >> 5;   // zrow block
  const int m0 = cx * 256;
  const int n0 = cy * 256;

  const int q = lane & 15;
  const int g = lane >> 4;
  const int rchunk = ((g ^ ((q >> 1) & 3)) << 3);  // swizzled 16B chunk, ushort units

  // staging constants: thread stages 16B at lds byte tid*16 (+8192 for B)
  const int srow = tid >> 2;                               // 0..127
  const int koff = (((tid & 3) ^ ((srow >> 1) & 3)) << 3); // swizzled k-elem offset

  floatx4 acc[8][4];
#pragma unroll
  for (int i = 0; i < 8; ++i)
#pragma unroll
    for (int j = 0; j < 4; ++j)
      acc[i][j] = (floatx4){0.f, 0.f, 0.f, 0.f};

  auto STAGE_A = [&](int kt) {
    unsigned short* s0 = lds + (kt & 3) * 16384 + tid * 8;
    const __hip_bfloat16* g0 = chv + ((size_t)(m0 + srow) << 8) + kt * 32 + koff;
    __builtin_amdgcn_global_load_lds((ga_u32*)g0, (ls_u32*)s0, 16, 0, 0);
    const __hip_bfloat16* g1 = g0 + (128 << 8);
    __builtin_amdgcn_global_load_lds((ga_u32*)g1, (ls_u32*)(s0 + 4096), 16, 0, 0);
  };
  auto STAGE_B = [&](int kt) {
    unsigned short* s0 = lds + (kt & 3) * 16384 + 8192 + tid * 8;
    const __hip_bfloat16* g0 = zh + ((size_t)(n0 + srow) << 8) + kt * 32 + koff;
    __builtin_amdgcn_global_load_lds((ga_u32*)g0, (ls_u32*)s0, 16, 0, 0);
    const __hip_bfloat16* g1 = g0 + (128 << 8);
    __builtin_amdgcn_global_load_lds((ga_u32*)g1, (ls_u32*)(s0 + 4096), 16, 0, 0);
  };
  auto LDA = [&](int slot, int i) -> short8 {
    int row = wm * 128 + i * 16 + q;
    return *(const short8*)(lds + slot * 16384 + row * 32 + rchunk);
  };
  auto LDB = [&](int slot, int j) -> short8 {
    int row = wn * 64 + j * 16 + q;
    return *(const short8*)(lds + slot * 16384 + 8192 + row * 32 + rchunk);
  };

  // prologue: stage K-tiles 0 and 1; wait kt0 landed (kt1's 4 stay in flight)
  STAGE_A(0); STAGE_B(0);
  STAGE_A(1); STAGE_B(1);
  asm volatile("s_waitcnt vmcnt(4)" ::: "memory");
  __builtin_amdgcn_s_barrier();
  asm volatile("" ::: "memory");

#pragma unroll
  for (int kt = 0; kt < 8; ++kt) {
    const int slot = kt & 3;
    short8 bf[4], af[8];
    // single region per kt: reads + prefetch-issue + MFMA (no internal barrier)
#pragma unroll
    for (int j = 0; j < 4; ++j) bf[j] = LDB(slot, j);
#pragma unroll
    for (int i = 0; i < 8; ++i) af[i] = LDA(slot, i);
    if (kt + 2 < 8) { STAGE_A(kt + 2); STAGE_B(kt + 2); }
    __builtin_amdgcn_s_setprio(1);
#pragma unroll
    for (int i = 0; i < 8; ++i)
#pragma unroll
      for (int j = 0; j < 4; ++j)
        acc[i][j] = __builtin_amdgcn_mfma_f32_16x16x32_bf16(af[i], bf[j], acc[i][j], 0, 0, 0);
    __builtin_amdgcn_s_setprio(0);
    // boundary: kt+1 must be landed everywhere; keep kt+2's 4 loads in flight
    if (kt < 6) {
      asm volatile("s_waitcnt vmcnt(4)" ::: "memory");
    } else if (kt == 6) {
      asm volatile("s_waitcnt vmcnt(0)" ::: "memory");
    }
    asm volatile("" ::: "memory");
    __builtin_amdgcn_s_barrier();
    asm volatile("" ::: "memory");
  }

  // ---- epilogue: fused argmin (deterministic, no atomics) ----
  float nrm[8][4];
#pragma unroll
  for (int i = 0; i < 8; ++i)
#pragma unroll
    for (int r = 0; r < 4; ++r)
      nrm[i][r] = norms[m0 + wm * 128 + i * 16 + g * 4 + r];

  u64* best2 = (u64*)lds;  // [256 zrows][2 wm]
#pragma unroll
  for (int j = 0; j < 4; ++j) {
    float best = __builtin_inff();
    int bc = 0;
    // ascending code order => strict < keeps smallest code on ties
#pragma unroll
    for (int i = 0; i < 8; ++i)
#pragma unroll
      for (int r = 0; r < 4; ++r) {
        float sc = fmaf(acc[i][j][r], -2.0f, nrm[i][r]);
        int cd = m0 + wm * 128 + i * 16 + g * 4 + r;
        if (sc < best) { best = sc; bc = cd; }
      }
    uint32_t u = __float_as_uint(best);
    u ^= ((uint32_t)((int32_t)u >> 31) | 0x80000000u);  // monotone-sortable
    u64 p = ((u64)u << 32) | (uint32_t)bc;
#pragma unroll
    for (int off = 16; off < 64; off <<= 1) {
      u64 o = (u64)__shfl_xor((long long)p, off);
      p = o < p ? o : p;
    }
    if (lane < 16) best2[(size_t)(wn * 64 + j * 16 + lane) * 2 + wm] = p;
  }
  __syncthreads();
  if (tid < 256) {
    u64 a = best2[tid * 2], b = best2[tid * 2 + 1];
    partial[(size_t)cx * NROWS + n0 + tid] = a < b ? a : b;
  }
}

// ---------------- stage-2: reduce 32 code-block partials -> final code ----------------
__global__ __launch_bounds__(256) void reduce_amin(const u64* __restrict__ partial,
                                                   uint32_t* __restrict__ codei)
{
  const int n = blockIdx.x * 256 + threadIdx.x;
  u64 m = partial[n];
#pragma unroll 4
  for (int x = 1; x < 32; ++x) {
    u64 v = partial[(size_t)x * NROWS + n];
    m = v < m ? v : m;
  }
  codei[n] = (uint32_t)m;
}

// ---------------- gather + output + per-block loss partials (x4 vectorized) ----------------
__global__ __launch_bounds__(256) void gather_out(
    const float* __restrict__ z, const float* __restrict__ cb,
    const uint32_t* __restrict__ codei,
    float* __restrict__ out, float* __restrict__ partial)
{
  const int t = threadIdx.x;
  const int e0 = (blockIdx.x * 256 + t) * 4;
  const int d = (e0 >> 10) & 255;
  const int nb = (e0 >> 18) << 10;  // b*1024
  const int hw = e0 & 1023;
  floatx4 zv = *(const floatx4*)&z[e0];
  uint4v kv = *(const uint4v*)&codei[nb + hw];
  floatx4 qv;
#pragma unroll
  for (int m = 0; m < 4; ++m)
    qv[m] = cb[((size_t)kv[m] << 8) + d];
  *(floatx4*)&out[e0] = qv;
  float s = 0.f;
#pragma unroll
  for (int m = 0; m < 4; ++m) {
    float df = zv[m] - qv[m];
    s += df * df;
  }
#pragma unroll
  for (int off = 32; off; off >>= 1) s += __shfl_down(s, off);
  __shared__ float ps[4];
  if ((t & 63) == 0) ps[t >> 6] = s;
  __syncthreads();
  if (t == 0) partial[blockIdx.x] = ps[0] + ps[1] + ps[2] + ps[3];
}

// ---------------- deterministic final reduction + scalar outputs ----------------
__global__ __launch_bounds__(256) void finalize(const float* __restrict__ partial,
                                                float* __restrict__ out)
{
  const int t = threadIdx.x;
  float s = 0.f;
  for (int i = t; i < QELEMS / 1024; i += 256) s += partial[i];
#pragma unroll
  for (int off = 32; off; off >>= 1) s += __shfl_down(s, off);
  __shared__ float ps[4];
  if ((t & 63) == 0) ps[t >> 6] = s;
  __syncthreads();
  if (t == 0) {
    float m = (ps[0] + ps[1] + ps[2] + ps[3]) / (float)QELEMS;
    out[QELEMS] = m;             // codebook_loss
    out[QELEMS + 1] = 0.2f * m;  // commitment_loss
  }
}

extern "C" void kernel_launch(void* const* d_in, const int* in_sizes, int n_in,
                              void* d_out, int out_size, void* d_ws, size_t ws_size,
                              hipStream_t stream)
{
  const float* z = (const float*)d_in[0];
  const float* cb = (const float*)d_in[1];
  float* out = (float*)d_out;
  char* ws = (char*)d_ws;

  // ws layout (bytes)
  __hip_bfloat16* zh = (__hip_bfloat16*)(ws + 0);        // 16,777,216
  __hip_bfloat16* chv = (__hip_bfloat16*)(ws + 16777216); //  4,194,304
  float* norms = (float*)(ws + 20971520);                 //     32,768
  u64* pamin = (u64*)(ws + 21004288);                     //  8,388,608 (32 x 32768 u64)
  uint32_t* codei = (uint32_t*)(ws + 29392896);           //    131,072
  float* lpart = (float*)(ws + 29523968);                 //     32,768
  // total: 29,556,736 bytes

  prep_z<<<dim3(32, 8, 4), 256, 0, stream>>>(z, zh);
  prep_cb<<<NCODE, 256, 0, stream>>>(cb, chv, norms);
  gemm_argmin<<<4096, 512, 0, stream>>>(zh, chv, norms, pamin);
  reduce_amin<<<NROWS / 256, 256, 0, stream>>>(pamin, codei);
  gather_out<<<QELEMS / 1024, 256, 0, stream>>>(z, cb, codei, out, lpart);
  finalize<<<1, 256, 0, stream>>>(lpart, out);
}